// Round 12
// baseline (691.360 us; speedup 1.0000x reference)
//
#include <hip/hip_runtime.h>
#include <hip/hip_bf16.h>

// GGNN encoder: N=10000, H=512, T=4, E=40000, L=2 x 2 timesteps.
// fp32 inputs, fp32 output, bf16 MFMA internally.
//
// r23: GATHER-FIRST restructure (linearity of message passing).
//   inc = segsum(Msg) with Msg = h@W_t^T  ==  inc = Σ_t segsum(h) @ W_t^T.
//   Old: gemm0 (N x 2048, K=512, 21.5 GF, ~42us) + gather of 163MB from
//   41MB L3-resident Msg (~18us). New: gather_h sums h rows (same read
//   count, but h = 10MB -> L2-friendly) into S (N x T*512 bf16), then
//   gemm<2>: inc = S_flat @ Wcat (K=2048, 10.7 GF -- HALF the FLOPs; Wcat
//   is just Wmsg repacked along K). cnt*b_msg folds into the gemm<2>
//   epilogue (cnt + bm staged in LDS, 4 FMAs/element). gemm1 untouched.
//
// Per step (2 GEMM dispatches):
//   S    = per-type gather-sum of h      (N x 2048 bf16)   [gather_h]
//   inc  = S @ Wcat^T + cnt*bm           (N x 512)         [MODE 2]
//   h'   = fused GRU GEMM: [inc|h] @ Wrznh^T (gate-interleaved)
//          + split epilogue -> h (bf16)                    [MODE 1]
// Final: FC + column-max fused [MODE 3] -> writeout.
//
// Carried (r22 structure, 559us baseline): 3 waves/SIMD occupancy
// (__launch_bounds__(256,3), per-s-slab A frags, VGPR 84 + 64 AGPR),
// fused GRU epilogue (gate-interleaved WrznhPK, per-kt j-skip), split
// (a,z)-LDS blend with coalesced h reads, no-h32, row-per-XCD swizzle,
// involutive LDS bank swizzle on A staging, BK=64, 3 rotating 16KB LDS
// bufs, depth-2 ping-pong B regs, ONE barrier per K-iter, vmcnt(20)/(8).

#define NN 10000
#define HD 512
#define NT 4
#define NE 40000
#define CAP 24          // max edges per (target,type); P(Poisson(4)>24)~1e-14/bin
#define GYROWS 80       // padded to multiple of 8 for XCD swizzle (79 used)

typedef __bf16 bf16x8 __attribute__((ext_vector_type(8)));
typedef float f32x4 __attribute__((ext_vector_type(4)));
union V16 { int4 i; bf16x8 b; };

typedef __attribute__((address_space(1))) const unsigned int gu32;
typedef __attribute__((address_space(3))) unsigned int lu32;
__device__ __forceinline__ void gll16(const void* g, void* l) {
    __builtin_amdgcn_global_load_lds((gu32*)g, (lu32*)l, 16, 0, 0);
}

__device__ __forceinline__ float bfl(__bf16 v) { return (float)v; }

// pack 8 fp32 -> int4 of 8 bf16
__device__ __forceinline__ int4 cvt8(const float* __restrict__ s) {
    float4 v0 = *(const float4*)s, v1 = *(const float4*)(s + 4);
    V16 o;
    o.b[0] = (__bf16)v0.x; o.b[1] = (__bf16)v0.y; o.b[2] = (__bf16)v0.z; o.b[3] = (__bf16)v0.w;
    o.b[4] = (__bf16)v1.x; o.b[5] = (__bf16)v1.y; o.b[6] = (__bf16)v1.z; o.b[7] = (__bf16)v1.w;
    return o.i;
}

// Packed-W layout: [ct][kt32][s], s=0..511: wc=s>>8, j=(s>>6)&3, lane=s&63.
// Entry = int4 of W[pc][kt32*32+quad*8 .. +8], pc = ct*128+wc*64+j*16+(lane&15).
__device__ __forceinline__ void pk_decode(int rem, int KTbits, int& col, int& kk) {
    int ct = rem >> (KTbits + 9);
    int r2 = rem & ((1 << (KTbits + 9)) - 1);
    int kt = r2 >> 9, s = r2 & 511;
    int lane = s & 63;
    col = ct * 128 + ((s >> 8) << 6) + (((s >> 6) & 3) << 4) + (lane & 15);
    kk = kt * 32 + ((lane >> 4) & 3) * 8;
}

// ---------------- fused prep: pack weights, init, bins ----------------------
__global__ void prep_all(const float* __restrict__ Wmsg, const float* __restrict__ Wih,
                         const float* __restrict__ Whh, const float* __restrict__ fcW,
                         const float* __restrict__ x, const int* __restrict__ edges,
                         int4* __restrict__ WiPK, int4* __restrict__ WrznhPK,
                         int4* __restrict__ WfPK,
                         __hip_bfloat16* __restrict__ ab,
                         int* __restrict__ bcnt, int* __restrict__ bins) {
    int blk = blockIdx.x, tid = threadIdx.x;
    if (blk < 1024) {            // WiPK: per layer 4ct x 64kt32 x 512 = 131072
        // inc GEMM weights: K = (t,h) in [0,2048); entry = Wmsg[l][t][col][h..h+8]
        int g = blk * 256 + tid;
        int l = g >> 17, rem = g & 131071;
        int col, kk; pk_decode(rem, 6, col, kk);
        WiPK[g] = cvt8(Wmsg + (size_t)l * 1048576 + (size_t)(kk >> 9) * 262144
                       + (size_t)col * 512 + (kk & 511));
        return;
    }
    blk -= 1024;
    if (blk < 2048) {            // WrznhPK: per layer 16ct x 32kt x 512 = 262144
        // GATE-INTERLEAVED: packed col pc -> gate g=(pc>>4)&3,
        // hcol = (bcol*2 + wc)*16 + lm, bcol=pc>>7, wc=(pc>>6)&1, lm=pc&15.
        int g = blk * 256 + tid;
        int l = g >> 18, rem = g & 262143;
        int col, kk; pk_decode(rem, 5, col, kk);
        int gate = (col >> 4) & 3;
        int hcol = ((col >> 7) * 2 + ((col >> 6) & 1)) * 16 + (col & 15);
        int4 v = make_int4(0, 0, 0, 0);
        if (kk < 512) {
            // inc-half: W_ih rows {r:hcol, z:512+hcol, i_n:1024+hcol}; hn=0
            if (gate < 3) v = cvt8(Wih + (size_t)l * 786432 + (size_t)(gate * 512 + hcol) * 512 + kk);
        } else {
            // h-half: W_hh rows {r:hcol, z:512+hcol, hn:1024+hcol}; i_n=0
            if (gate < 2) v = cvt8(Whh + (size_t)l * 786432 + (size_t)(gate * 512 + hcol) * 512 + (kk - 512));
            else if (gate == 3) v = cvt8(Whh + (size_t)l * 786432 + (size_t)(1024 + hcol) * 512 + (kk - 512));
        }
        WrznhPK[g] = v;
        return;
    }
    blk -= 2048;
    if (blk < 128) {             // WfPK: 4ct x 16kt x 512 = 32768
        int g = blk * 256 + tid;
        int col, kk; pk_decode(g, 4, col, kk);
        WfPK[g] = cvt8(fcW + (size_t)col * 512 + kk);
        return;
    }
    blk -= 128;
    if (blk < 5000) {            // init: abA h-slot <- bf16(x)
        int i = blk * 1024 + tid * 4;
        float4 v = *(const float4*)(x + i);
        int m = i >> 9, c = i & 511;
        __hip_bfloat16 o[4] = {__float2bfloat16(v.x), __float2bfloat16(v.y),
                               __float2bfloat16(v.z), __float2bfloat16(v.w)};
        *(ulong1*)(ab + (size_t)m * 1024 + 512 + c) = *(ulong1*)o;
        return;
    }
    blk -= 5000;
    {                            // build_bins
        int i = blk * 256 + tid;
        if (i >= NT * NE) return;
        int src = edges[2 * i], tgt = edges[2 * i + 1];
        int t = i / NE;
        int b = tgt * NT + t;
        int pos = atomicAdd(&bcnt[b], 1);
        if (pos < CAP) bins[(size_t)b * CAP + pos] = src;
    }
}

// ---------------- gather_h: S[n][t*512+c] = sum_{src in bin(n,t)} h[src][c] --
__global__ __launch_bounds__(256) void gather_h(
    const int* __restrict__ bins, const int* __restrict__ bcnt,
    const __hip_bfloat16* __restrict__ h,      // cur+512, row stride 1024
    __hip_bfloat16* __restrict__ S) {
    int wave = threadIdx.x >> 6, lane = threadIdx.x & 63;
    int n = blockIdx.x * 4 + wave;
    int co = lane * 8;
#pragma unroll
    for (int t = 0; t < NT; ++t) {
        int bi = n * NT + t;
        int cnt = bcnt[bi]; if (cnt > CAP) cnt = CAP;
        const int* bl = bins + (size_t)bi * CAP;
        float acc[8] = {0, 0, 0, 0, 0, 0, 0, 0};
        for (int e = 0; e < cnt; ++e) {
            int src = bl[e];
            V16 v; v.i = *(const int4*)(h + (size_t)src * 1024 + co);
#pragma unroll
            for (int k = 0; k < 8; ++k) acc[k] += (float)v.b[k];
        }
        V16 o;
#pragma unroll
        for (int k = 0; k < 8; ++k) o.b[k] = (__bf16)acc[k];
        *(int4*)(S + (size_t)n * 2048 + t * 512 + co) = o.i;
    }
}

// ---------------- monotone-uint float max encoding ----------------
__device__ __forceinline__ unsigned fenc(float f) {
    unsigned b = __float_as_uint(f);
    return b ^ (((int)b >> 31) | 0x80000000u);
}
__device__ __forceinline__ float fdec(unsigned u) {
    unsigned b = (u & 0x80000000u) ? (u ^ 0x80000000u) : ~u;
    return __uint_as_float(b);
}

// ---------------- GEMM: out = A(NNxK,lda) @ W^T, 128x128 tile, BK=64 ---------
// ONE barrier per K-iter; depth-2 A (3 x 16KB LDS bufs, gll16), ping-pong
// B regs, 3 waves/SIMD. MODE 0: plain bf16 out. MODE 1: fused GRU.
// MODE 2: inc GEMM (K=2048 over S) + cnt*bm bias epilogue. MODE 3: FC+max.
template<int MODE>
__global__ __launch_bounds__(256, 3) void gemm(
    const __hip_bfloat16* __restrict__ A, int lda, int K,
    const int4* __restrict__ Wpk,
    const float* __restrict__ b0, const float* __restrict__ b1,
    __hip_bfloat16* __restrict__ obf, int ldo,
    const int* __restrict__ bcnt, unsigned* __restrict__ om) {
    __shared__ int4 sA4[3][1024];             // 48 KB: A staging; epilogue scratch
    __shared__ unsigned sm[128];
    __hip_bfloat16* lds = (__hip_bfloat16*)sA4;   // MODE 0/2 epilogue view
    float2* ldsZ = (float2*)sA4;                  // MODE 1 epilogue view (a,z)

    const int NB = (MODE >= 2) ? 4 : 16;      // bcols in grid
    int bid = blockIdx.x;
    int xcd = bid & 7, kq = bid >> 3;
    int bcol = kq % NB;
    int brow = xcd + 8 * (kq / NB);           // 0..79 exactly covered
    int m0 = brow * 128, n0 = bcol * 128;

    int tid = threadIdx.x;
    int lane = tid & 63, wave = tid >> 6;
    int wr = wave >> 1, wc = wave & 1;
    int lm = lane & 15, quad = lane >> 4;
    int qx = (lm >> 1) & 3;                   // read-side bank swizzle

    const int KT32 = K >> 5;
    const int KT = K >> 6;       // BK64 tiles
    const int kend = KT;         // uniform (MODE 1 zero-structure handled per-j)
    const int4* Wp = Wpk + ((size_t)bcol * KT32 << 9) + wc * 256 + lane;

    // LDS per tile = two 32-k sub-slabs of 512 int4; bank-swizzled placement.
    auto issueA = [&](int kt, int p) {
        int k0 = kt << 6;
#pragma unroll
        for (int it = 0; it < 4; ++it) {
            int idx = it * 256 + tid;
            int s = idx >> 9, rem = idx & 511;
            int row = rem >> 2;
            int kc = (rem & 3) ^ ((row >> 1) & 3);    // src-side swizzle
            int gm = m0 + row; gm = gm < NN ? gm : NN - 1;
            gll16(A + (size_t)gm * lda + k0 + s * 32 + kc * 8,
                  (__hip_bfloat16*)(sA4[p]) + idx * 8);
        }
    };
    auto loadB = [&](int kt, int4 (&bb)[2][4]) {
#pragma unroll
        for (int s = 0; s < 2; ++s) {
            const int4* wn = Wp + ((size_t)(2 * kt + s) << 9);
#pragma unroll
            for (int j = 0; j < 4; ++j) bb[s][j] = wn[j * 64];
        }
    };

    f32x4 acc[4][4] = {};
    int4 bb0[2][4], bb1[2][4];
    issueA(0, 0);
    issueA(1, 1);
    loadB(0, bb0);

    auto ktbody = [&](int kt, int4 (&bbCur)[2][4], int4 (&bbNxt)[2][4]) {
        int p = kt % 3;
        if (kt + 1 < kend) loadB(kt + 1, bbNxt);
        __builtin_amdgcn_sched_barrier(0);
        if (kt + 1 < kend) __builtin_amdgcn_s_waitcnt(0x4F74);  // vmcnt(20): A(kt) retired
        else               __builtin_amdgcn_s_waitcnt(0x0F78);  // vmcnt(8) last iter
        __builtin_amdgcn_s_barrier();   // tile kt staged; all reads of buf
                                        // (kt-1)%3 complete (consumed pre-barrier)
        __builtin_amdgcn_sched_barrier(0);   // pins issueA below the barrier
        if (kt + 2 < kend) issueA(kt + 2, (kt + 2) % 3);  // overwrites (kt-1)%3: safe
        // per-s-slab A fragments (16 VGPR working set, not 32)
#pragma unroll
        for (int s = 0; s < 2; ++s) {
            V16 a[4];
#pragma unroll
            for (int i = 0; i < 4; ++i)
                a[i].i = sA4[p][s * 512 + (wr * 64 + i * 16 + lm) * 4 + (quad ^ qx)];
#pragma unroll
            for (int i = 0; i < 4; ++i)
#pragma unroll
                for (int j = 0; j < 4; ++j) {
                    if (MODE == 1) {   // structural zeros: i_n no h-half, hn no inc-half
                        if (j == 2 && kt >= 8) continue;
                        if (j == 3 && kt < 8) continue;
                    }
                    V16 b; b.i = bbCur[s][j];
                    acc[i][j] = __builtin_amdgcn_mfma_f32_16x16x32_bf16(a[i].b, b.b, acc[i][j], 0, 0, 0);
                }
        }
        __builtin_amdgcn_sched_barrier(0);
    };

    for (int k2 = 0; k2 < kend; k2 += 2) {       // kend always even (8/16/32)
        ktbody(k2, bb0, bb1);
        ktbody(k2 + 1, bb1, bb0);
    }

    if (MODE == 0 || MODE == 2) {
        __syncthreads();   // acc final; sA4 reusable as scratch
        if (MODE == 2) {
            // bias: acc[i][j][r] += sum_t cnt[m][t] * bm[t][n0+c]
            int* ldsCnt = (int*)((char*)sA4 + 40960);      // 512 ints (2KB)
            float* ldsBm = (float*)((char*)sA4 + 43008);   // 512 f32 (2KB)
            if (tid < 128) {
                int m = m0 + tid;
                int4 c4 = make_int4(0, 0, 0, 0);
                if (m < NN) c4 = *(const int4*)(bcnt + (size_t)m * 4);
                c4.x = c4.x > CAP ? CAP : c4.x;
                c4.y = c4.y > CAP ? CAP : c4.y;
                c4.z = c4.z > CAP ? CAP : c4.z;
                c4.w = c4.w > CAP ? CAP : c4.w;
                *(int4*)(ldsCnt + tid * 4) = c4;
            } else if (tid < 256) {
                int i2 = tid - 128;
                int t = i2 >> 5, cq = (i2 & 31) << 2;
                *(float4*)(ldsBm + t * 128 + cq) = *(const float4*)(b0 + t * 512 + n0 + cq);
            }
            __syncthreads();
            float bmv[4][4];
#pragma unroll
            for (int j = 0; j < 4; ++j) {
                int c = wc * 64 + j * 16 + lm;
#pragma unroll
                for (int t = 0; t < 4; ++t) bmv[j][t] = ldsBm[t * 128 + c];
            }
#pragma unroll
            for (int i = 0; i < 4; ++i)
#pragma unroll
                for (int r = 0; r < 4; ++r) {
                    int rloc = wr * 64 + i * 16 + quad * 4 + r;
                    int4 cc = *(const int4*)(ldsCnt + rloc * 4);
#pragma unroll
                    for (int j = 0; j < 4; ++j)
                        acc[i][j][r] += (float)cc.x * bmv[j][0] + (float)cc.y * bmv[j][1]
                                      + (float)cc.z * bmv[j][2] + (float)cc.w * bmv[j][3];
                }
            __syncthreads();
        }
        // LDS-transpose epilogue, 2 row-phases of 64x128 bf16 (coalesced stores)
#pragma unroll
        for (int ph = 0; ph < 2; ++ph) {
            if (wr == ph) {
#pragma unroll
                for (int j = 0; j < 4; ++j) {
                    int c = wc * 64 + j * 16 + lm;
#pragma unroll
                    for (int i = 0; i < 4; ++i)
#pragma unroll
                        for (int r = 0; r < 4; ++r)
                            lds[(i * 16 + quad * 4 + r) * 128 + c] = __float2bfloat16(acc[i][j][r]);
                }
            }
            __syncthreads();
#pragma unroll
            for (int q = 0; q < 4; ++q) {
                int idx = q * 256 + tid;
                int rl = idx >> 4, c16 = idx & 15;
                int m = m0 + ph * 64 + rl;
                if (m < NN)
                    *(int4*)(obf + (size_t)m * ldo + n0 + c16 * 8) =
                        *(const int4*)(lds + rl * 128 + c16 * 8);
            }
            __syncthreads();
        }
    } else if (MODE == 1) {
        // fused GRU, split blend: epilogue computes a=(1-z)*n and z (fp32),
        // stores (a,z) pairs to LDS; writeout phase blends with COALESCED
        // bf16 h loads from the A operand's h-half.
        __syncthreads();   // acc final; sA4 reusable as scratch
        int c32 = wc * 16 + lm;
        int hcol = bcol * 32 + c32;
        float rb = b0[hcol] + b1[hcol];
        float zb = b0[512 + hcol] + b1[512 + hcol];
        float ib = b0[1024 + hcol];
        float hb = b1[1024 + hcol];
#pragma unroll
        for (int i = 0; i < 4; ++i)
#pragma unroll
            for (int r = 0; r < 4; ++r) {
                int rloc = wr * 64 + i * 16 + quad * 4 + r;
                float rr = 1.f / (1.f + __expf(-(acc[i][0][r] + rb)));
                float zz = 1.f / (1.f + __expf(-(acc[i][1][r] + zb)));
                float nx = (acc[i][2][r] + ib) + rr * (acc[i][3][r] + hb);
                float n = 1.f - 2.f / (__expf(2.f * nx) + 1.f);
                ldsZ[rloc * 34 + c32] = make_float2((1.f - zz) * n, zz);
            }
        __syncthreads();
        // coalesced writeout: 128 rows x 32 cols bf16 (next step's A h-slot);
        // h read 8B/thread from A[m][512+bcol*32+c4..] (64B per 8 threads).
#pragma unroll
        for (int q = 0; q < 4; ++q) {
            int idx = q * 256 + tid;              // 1024 4-col units
            int rl = idx >> 3, c4 = (idx & 7) * 4;
            int m = m0 + rl;
            if (m < NN) {
                ulong1 hraw = *(const ulong1*)(A + (size_t)m * lda + 512 + bcol * 32 + c4);
                const __bf16* hb4 = (const __bf16*)&hraw;
                const float2* pz = ldsZ + rl * 34 + c4;
                __hip_bfloat16 ob[4];
#pragma unroll
                for (int e = 0; e < 4; ++e) {
                    float2 az = pz[e];
                    ob[e] = __float2bfloat16(az.x + az.y * bfl(hb4[e]));
                }
                *(ulong1*)(obf + (size_t)m * ldo + bcol * 32 + c4) = *(ulong1*)ob;
            }
        }
    } else {   // MODE 3: FC + column max
        if (tid < 128) sm[tid] = 0;
        __syncthreads();
#pragma unroll
        for (int j = 0; j < 4; ++j) {
            int c = wc * 64 + j * 16 + lm;
            float bias = b0[n0 + c];
            float mx = -INFINITY;
#pragma unroll
            for (int i = 0; i < 4; ++i) {
                int r0 = m0 + wr * 64 + i * 16 + quad * 4;
#pragma unroll
                for (int r = 0; r < 4; ++r) {
                    int m = r0 + r;
                    if (m < NN) mx = fmaxf(mx, acc[i][j][r] + bias);
                }
            }
            atomicMax(&sm[c], fenc(mx));
        }
        __syncthreads();
        if (tid < 128) atomicMax(&om[n0 + tid], sm[tid]);
    }
}

__global__ void writeout(const unsigned* __restrict__ om, float* __restrict__ o) {
    int c = threadIdx.x;
    o[c] = fdec(om[c]);
}

// ---------------- launch ----------------
extern "C" void kernel_launch(void* const* d_in, const int* in_sizes, int n_in,
                              void* d_out, int out_size, void* d_ws, size_t ws_size,
                              hipStream_t stream) {
    (void)in_sizes; (void)n_in; (void)out_size; (void)ws_size;
    const float* x    = (const float*)d_in[0];
    const int*   edges= (const int*)d_in[1];
    const float* Wmsg = (const float*)d_in[2];
    const float* bmsg = (const float*)d_in[3];
    const float* Wih  = (const float*)d_in[4];
    const float* Whh  = (const float*)d_in[5];
    const float* bih  = (const float*)d_in[6];
    const float* bhh  = (const float*)d_in[7];
    const float* fcW  = (const float*)d_in[8];
    const float* fcb  = (const float*)d_in[9];
    float* out = (float*)d_out;

    char* ws = (char*)d_ws;
    size_t off = 0;
    auto alloc = [&](size_t bytes) -> void* {
        void* p = ws + off; off += (bytes + 255) & ~(size_t)255; return p;
    };
    __hip_bfloat16* abA  = (__hip_bfloat16*)alloc((size_t)NN * 1024 * 2);   // 20.5 MB
    __hip_bfloat16* abB  = (__hip_bfloat16*)alloc((size_t)NN * 1024 * 2);   // 20.5 MB
    int*            bcnt = (int*)alloc((size_t)NN * NT * 4);                // 160 KB
    int*            bins = (int*)alloc((size_t)NN * NT * CAP * 4);          // 3.8 MB
    unsigned*       om   = (unsigned*)alloc(HD * 4);
    int4*           WiPK   = (int4*)alloc((size_t)2 * 131072 * 16);         // 4.2 MB
    int4*           WrznhPK= (int4*)alloc((size_t)2 * 262144 * 16);         // 8.4 MB
    int4*           WfPK   = (int4*)alloc((size_t)32768 * 16);              // 0.5 MB
    __hip_bfloat16* S    = (__hip_bfloat16*)alloc((size_t)NN * 2048 * 2);   // 41 MB
    // total ~99 MB

    hipMemsetAsync(bcnt, 0, (size_t)NN * NT * 4, stream);
    hipMemsetAsync(om, 0, HD * 4, stream);
    prep_all<<<1024 + 2048 + 128 + 5000 + 625, 256, 0, stream>>>(
        Wmsg, Wih, Whh, fcW, x, edges, WiPK, WrznhPK, WfPK, abA, bcnt, bins);

    for (int s = 0; s < 4; ++s) {
        int layer = s >> 1;
        __hip_bfloat16* cur = (s & 1) ? abB : abA;
        __hip_bfloat16* nxt = (s & 1) ? abA : abB;
        const int4* Wi = WiPK + (size_t)layer * 131072;
        const int4* Wz = WrznhPK + (size_t)layer * 262144;
        const float* bm = bmsg + (size_t)layer * 2048;
        const float* bi = bih + (size_t)layer * 1536;
        const float* bh = bhh + (size_t)layer * 1536;

        // S = per-type gather-sum of h
        gather_h<<<NN / 4, 256, 0, stream>>>(bins, bcnt, cur + 512, S);
        // inc = S @ Wcat^T + cnt*bm -> cur[0:512]   (K=2048, 10.7 GF)
        gemm<2><<<4 * GYROWS, 256, 0, stream>>>(S, 2048, 2048, Wi,
            bm, nullptr, cur, 1024, bcnt, nullptr);
        // fused GRU GEMM -> nxt h-slot (bf16)
        gemm<1><<<16 * GYROWS, 256, 0, stream>>>(cur, 1024, 1024, Wz,
            bi, bh, nxt + 512, 1024, nullptr, nullptr);
    }
    // FC + column max (final h in abA h-slot after 4 steps)
    gemm<3><<<4 * GYROWS, 256, 0, stream>>>(abA + 512, 1024, 512, WfPK,
        fcb, nullptr, nullptr, 0, nullptr, om);
    writeout<<<1, 512, 0, stream>>>(om, out);
}

// Round 13
// 690.482 us; speedup vs baseline: 1.0013x; 1.0013x over previous
//
#include <hip/hip_runtime.h>
#include <hip/hip_bf16.h>

// GGNN encoder: N=10000, H=512, T=4, E=40000, L=2 x 2 timesteps.
// fp32 inputs, fp32 output, bf16 MFMA internally.
//
// r24: REVERT r23 gather-first (320-block inc-GEMM starved: 1.25 blocks/CU,
//   69us; total K-iters invariant to the reshape so it can never win).
//   Back to r22 (559us: Msg GEMM + gather_msum + fused-GRU GEMM), plus ONE
//   lever: gemm<1> goes 8-WAVE / BN=256 (512 thr, 640 blocks, half the
//   total block-iters). Cost model from r14-r23: per-iter fixed cost
//   (~1540cyc @3-resident, ~2000 @1) dwarfs ~400cyc content -> fewer,
//   fatter iterations win. 8 waves = (wr, ct_off, wc); each wave one 64x64
//   tile; ct = bcol*2+ct_off so the W packing and prep are UNCHANGED.
//   A-LDS (128x64) now feeds 256 out-cols. acc stays 64 AGPR/wave.
//   vmcnt ladder re-derived (per-thread: 8 B + 2 A): steady vmcnt(18),
//   tail vmcnt(8). Epilogue: 2 phases over ct_off (ldsZ 128x32 per phase).
//   gemm<0>/gemm<3> stay exact r22 (A/B isolation).
//
// Carried (r22): 3 waves/SIMD for 4-wave modes (__launch_bounds__(256,3),
// per-s-slab A frags), fused GRU epilogue (gate-interleaved WrznhPK,
// per-kt j-skip), split (a,z)-LDS blend with coalesced h reads, no-h32,
// row-per-XCD swizzle, involutive LDS bank swizzle on A staging, BK=64,
// 3 rotating 16KB LDS bufs, depth-2 ping-pong B regs, ONE barrier/K-iter.

#define NN 10000
#define HD 512
#define NT 4
#define NE 40000
#define CAP 24          // max edges per (target,type); P(Poisson(4)>24)~1e-14/bin
#define GYROWS 80       // padded to multiple of 8 for XCD swizzle (79 used)

typedef __bf16 bf16x8 __attribute__((ext_vector_type(8)));
typedef float f32x4 __attribute__((ext_vector_type(4)));
union V16 { int4 i; bf16x8 b; };

typedef __attribute__((address_space(1))) const unsigned int gu32;
typedef __attribute__((address_space(3))) unsigned int lu32;
__device__ __forceinline__ void gll16(const void* g, void* l) {
    __builtin_amdgcn_global_load_lds((gu32*)g, (lu32*)l, 16, 0, 0);
}

__device__ __forceinline__ float bfl(__bf16 v) { return (float)v; }

// pack 8 fp32 -> int4 of 8 bf16
__device__ __forceinline__ int4 cvt8(const float* __restrict__ s) {
    float4 v0 = *(const float4*)s, v1 = *(const float4*)(s + 4);
    V16 o;
    o.b[0] = (__bf16)v0.x; o.b[1] = (__bf16)v0.y; o.b[2] = (__bf16)v0.z; o.b[3] = (__bf16)v0.w;
    o.b[4] = (__bf16)v1.x; o.b[5] = (__bf16)v1.y; o.b[6] = (__bf16)v1.z; o.b[7] = (__bf16)v1.w;
    return o.i;
}

// Packed-W layout: [ct][kt32][s], s=0..511: wc=s>>8, j=(s>>6)&3, lane=s&63.
// Entry = int4 of W[pc][kt32*32+quad*8 .. +8], pc = ct*128+wc*64+j*16+(lane&15).
__device__ __forceinline__ void pk_decode(int rem, int KTbits, int& col, int& kk) {
    int ct = rem >> (KTbits + 9);
    int r2 = rem & ((1 << (KTbits + 9)) - 1);
    int kt = r2 >> 9, s = r2 & 511;
    int lane = s & 63;
    col = ct * 128 + ((s >> 8) << 6) + (((s >> 6) & 3) << 4) + (lane & 15);
    kk = kt * 32 + ((lane >> 4) & 3) * 8;
}

// ---------------- fused prep: pack weights, init, bins ----------------------
__global__ void prep_all(const float* __restrict__ Wmsg, const float* __restrict__ Wih,
                         const float* __restrict__ Whh, const float* __restrict__ fcW,
                         const float* __restrict__ x, const int* __restrict__ edges,
                         int4* __restrict__ WmPK, int4* __restrict__ WrznhPK,
                         int4* __restrict__ WfPK,
                         __hip_bfloat16* __restrict__ ab,
                         int* __restrict__ bcnt, int* __restrict__ bins) {
    int blk = blockIdx.x, tid = threadIdx.x;
    if (blk < 1024) {            // WmPK: per layer 16ct x 16kt x 512 = 131072
        int g = blk * 256 + tid;
        int l = g >> 17, rem = g & 131071;
        int col, kk; pk_decode(rem, 4, col, kk);
        WmPK[g] = cvt8(Wmsg + (size_t)l * 1048576 + (size_t)col * 512 + kk);
        return;
    }
    blk -= 1024;
    if (blk < 2048) {            // WrznhPK: per layer 16ct x 32kt x 512 = 262144
        // GATE-INTERLEAVED: packed col pc -> gate g=(pc>>4)&3,
        // hcol = (bcol*2 + wc)*16 + lm, bcol=pc>>7, wc=(pc>>6)&1, lm=pc&15.
        int g = blk * 256 + tid;
        int l = g >> 18, rem = g & 262143;
        int col, kk; pk_decode(rem, 5, col, kk);
        int gate = (col >> 4) & 3;
        int hcol = ((col >> 7) * 2 + ((col >> 6) & 1)) * 16 + (col & 15);
        int4 v = make_int4(0, 0, 0, 0);
        if (kk < 512) {
            // inc-half: W_ih rows {r:hcol, z:512+hcol, i_n:1024+hcol}; hn=0
            if (gate < 3) v = cvt8(Wih + (size_t)l * 786432 + (size_t)(gate * 512 + hcol) * 512 + kk);
        } else {
            // h-half: W_hh rows {r:hcol, z:512+hcol, hn:1024+hcol}; i_n=0
            if (gate < 2) v = cvt8(Whh + (size_t)l * 786432 + (size_t)(gate * 512 + hcol) * 512 + (kk - 512));
            else if (gate == 3) v = cvt8(Whh + (size_t)l * 786432 + (size_t)(1024 + hcol) * 512 + (kk - 512));
        }
        WrznhPK[g] = v;
        return;
    }
    blk -= 2048;
    if (blk < 128) {             // WfPK: 4ct x 16kt x 512 = 32768
        int g = blk * 256 + tid;
        int col, kk; pk_decode(g, 4, col, kk);
        WfPK[g] = cvt8(fcW + (size_t)col * 512 + kk);
        return;
    }
    blk -= 128;
    if (blk < 5000) {            // init: abA h-slot <- bf16(x)
        int i = blk * 1024 + tid * 4;
        float4 v = *(const float4*)(x + i);
        int m = i >> 9, c = i & 511;
        __hip_bfloat16 o[4] = {__float2bfloat16(v.x), __float2bfloat16(v.y),
                               __float2bfloat16(v.z), __float2bfloat16(v.w)};
        *(ulong1*)(ab + (size_t)m * 1024 + 512 + c) = *(ulong1*)o;
        return;
    }
    blk -= 5000;
    {                            // build_bins
        int i = blk * 256 + tid;
        if (i >= NT * NE) return;
        int src = edges[2 * i], tgt = edges[2 * i + 1];
        int t = i / NE;
        int b = tgt * NT + t;
        int pos = atomicAdd(&bcnt[b], 1);
        if (pos < CAP) bins[(size_t)b * CAP + pos] = src;
    }
}

// ---------------- gather: inc[n][c] = sum_t sum_src Msg[src][t*512+c] + cnt*bm
__global__ __launch_bounds__(256) void gather_msum(
    const int* __restrict__ bins, const int* __restrict__ bcnt,
    const float* __restrict__ bm, const __hip_bfloat16* __restrict__ Msg,
    __hip_bfloat16* __restrict__ inc) {
    int wave = threadIdx.x >> 6, lane = threadIdx.x & 63;
    int n = blockIdx.x * 4 + wave;
    int co = lane * 8;
    float acc[8] = {0, 0, 0, 0, 0, 0, 0, 0};
#pragma unroll
    for (int t = 0; t < NT; ++t) {
        int bi = n * NT + t;
        int cnt = bcnt[bi]; if (cnt > CAP) cnt = CAP;
        const int* bl = bins + (size_t)bi * CAP;
        for (int e = 0; e < cnt; ++e) {
            int src = bl[e];
            V16 v; v.i = *(const int4*)(Msg + (size_t)src * 2048 + t * 512 + co);
#pragma unroll
            for (int k = 0; k < 8; ++k) acc[k] += (float)v.b[k];
        }
        float4 b0 = *(const float4*)(bm + t * 512 + co);
        float4 b1 = *(const float4*)(bm + t * 512 + co + 4);
        float fc = (float)cnt;
        acc[0] += fc * b0.x; acc[1] += fc * b0.y; acc[2] += fc * b0.z; acc[3] += fc * b0.w;
        acc[4] += fc * b1.x; acc[5] += fc * b1.y; acc[6] += fc * b1.z; acc[7] += fc * b1.w;
    }
    V16 o;
#pragma unroll
    for (int k = 0; k < 8; ++k) o.b[k] = (__bf16)acc[k];
    *(int4*)(inc + (size_t)n * 1024 + co) = o.i;
}

// ---------------- monotone-uint float max encoding ----------------
__device__ __forceinline__ unsigned fenc(float f) {
    unsigned b = __float_as_uint(f);
    return b ^ (((int)b >> 31) | 0x80000000u);
}
__device__ __forceinline__ float fdec(unsigned u) {
    unsigned b = (u & 0x80000000u) ? (u ^ 0x80000000u) : ~u;
    return __uint_as_float(b);
}

// ---------------- GEMM: out = A(NNxK,lda) @ W^T, BK=64 ----------------------
// MODE 0: 128x128 tile, 4 waves (r22).  MODE 1: 128x256 tile, 8 WAVES
// (wr, ct_off, wc); half the block-iters of r22's gemm1.  MODE 3: r22.
// ONE barrier per K-iter; depth-2 A (3 x 16KB LDS bufs), ping-pong B regs.
template<int MODE>
__global__ __launch_bounds__((MODE == 1) ? 512 : 256, (MODE == 1) ? 2 : 3) void gemm(
    const __hip_bfloat16* __restrict__ A, int lda, int K,
    const int4* __restrict__ Wpk,
    const float* __restrict__ b0, const float* __restrict__ b1,
    __hip_bfloat16* __restrict__ obf, int ldo,
    unsigned* __restrict__ om) {
    __shared__ int4 sA4[3][1024];             // 48 KB: A staging; epilogue scratch
    __shared__ unsigned sm[128];
    __hip_bfloat16* lds = (__hip_bfloat16*)sA4;   // MODE 0 epilogue view
    float2* ldsZ = (float2*)sA4;                  // MODE 1 epilogue view (a,z)

    const int NB = (MODE == 3) ? 4 : ((MODE == 1) ? 8 : 16);
    const int NTH = (MODE == 1) ? 512 : 256;
    int bid = blockIdx.x;
    int xcd = bid & 7, kq = bid >> 3;
    int bcol = kq % NB;
    int brow = xcd + 8 * (kq / NB);           // 0..79 exactly covered
    int m0 = brow * 128, n0 = bcol * 128;

    int tid = threadIdx.x;
    int lane = tid & 63, wave = tid >> 6;
    int wr, wc, ct_off;
    if (MODE == 1) { wr = wave >> 2; ct_off = (wave >> 1) & 1; wc = wave & 1; }
    else           { wr = wave >> 1; ct_off = 0;               wc = wave & 1; }
    int lm = lane & 15, quad = lane >> 4;
    int qx = (lm >> 1) & 3;                   // read-side bank swizzle

    const int KT32 = K >> 5;
    const int KT = K >> 6;       // BK64 tiles
    const int kend = KT;         // uniform (MODE 1 zero-structure handled per-j)
    int ct = (MODE == 1) ? (bcol * 2 + ct_off) : bcol;
    const int4* Wp = Wpk + ((size_t)ct * KT32 << 9) + wc * 256 + lane;

    // LDS per tile = two 32-k sub-slabs of 512 int4; bank-swizzled placement.
    auto issueA = [&](int kt, int p) {
        int k0 = kt << 6;
#pragma unroll
        for (int it = 0; it < 1024 / NTH; ++it) {
            int idx = it * NTH + tid;
            int s = idx >> 9, rem = idx & 511;
            int row = rem >> 2;
            int kc = (rem & 3) ^ ((row >> 1) & 3);    // src-side swizzle
            int gm = m0 + row; gm = gm < NN ? gm : NN - 1;
            gll16(A + (size_t)gm * lda + k0 + s * 32 + kc * 8,
                  (__hip_bfloat16*)(sA4[p]) + idx * 8);
        }
    };
    auto loadB = [&](int kt, int4 (&bb)[2][4]) {
#pragma unroll
        for (int s = 0; s < 2; ++s) {
            const int4* wn = Wp + ((size_t)(2 * kt + s) << 9);
#pragma unroll
            for (int j = 0; j < 4; ++j) bb[s][j] = wn[j * 64];
        }
    };

    f32x4 acc[4][4] = {};
    int4 bb0[2][4], bb1[2][4];
    issueA(0, 0);
    issueA(1, 1);
    loadB(0, bb0);

    auto ktbody = [&](int kt, int4 (&bbCur)[2][4], int4 (&bbNxt)[2][4]) {
        int p = kt % 3;
        if (kt + 1 < kend) loadB(kt + 1, bbNxt);
        __builtin_amdgcn_sched_barrier(0);
        // FIFO per thread: steady outstanding {A(kt),B(kt),A(kt+1),B(kt+1)};
        // retire through A(kt). MODE1: 2A+8B per iter -> vmcnt(18); else 4A+8B
        // -> vmcnt(20). Last iter: vmcnt(8) (B(kt) auto-waited at use).
        if (kt + 1 < kend) __builtin_amdgcn_s_waitcnt((MODE == 1) ? 0x4F72 : 0x4F74);
        else               __builtin_amdgcn_s_waitcnt(0x0F78);
        __builtin_amdgcn_s_barrier();   // tile kt staged; all reads of buf
                                        // (kt-1)%3 complete (consumed pre-barrier)
        __builtin_amdgcn_sched_barrier(0);   // pins issueA below the barrier
        if (kt + 2 < kend) issueA(kt + 2, (kt + 2) % 3);  // overwrites (kt-1)%3: safe
        // per-s-slab A fragments (16 VGPR working set)
#pragma unroll
        for (int s = 0; s < 2; ++s) {
            V16 a[4];
#pragma unroll
            for (int i = 0; i < 4; ++i)
                a[i].i = sA4[p][s * 512 + (wr * 64 + i * 16 + lm) * 4 + (quad ^ qx)];
#pragma unroll
            for (int i = 0; i < 4; ++i)
#pragma unroll
                for (int j = 0; j < 4; ++j) {
                    if (MODE == 1) {   // structural zeros: i_n no h-half, hn no inc-half
                        if (j == 2 && kt >= 8) continue;
                        if (j == 3 && kt < 8) continue;
                    }
                    V16 b; b.i = bbCur[s][j];
                    acc[i][j] = __builtin_amdgcn_mfma_f32_16x16x32_bf16(a[i].b, b.b, acc[i][j], 0, 0, 0);
                }
        }
        __builtin_amdgcn_sched_barrier(0);
    };

    for (int k2 = 0; k2 < kend; k2 += 2) {       // kend always even (8 or 16)
        ktbody(k2, bb0, bb1);
        ktbody(k2 + 1, bb1, bb0);
    }

    if (MODE == 0) {
        // LDS-transpose epilogue, 2 row-phases of 64x128 bf16 (coalesced stores)
        __syncthreads();   // acc final; sA4 reusable as scratch
#pragma unroll
        for (int ph = 0; ph < 2; ++ph) {
            if (wr == ph) {
#pragma unroll
                for (int j = 0; j < 4; ++j) {
                    int c = wc * 64 + j * 16 + lm;
#pragma unroll
                    for (int i = 0; i < 4; ++i)
#pragma unroll
                        for (int r = 0; r < 4; ++r)
                            lds[(i * 16 + quad * 4 + r) * 128 + c] = __float2bfloat16(acc[i][j][r]);
                }
            }
            __syncthreads();
#pragma unroll
            for (int q = 0; q < 4; ++q) {
                int idx = q * 256 + tid;
                int rl = idx >> 4, c16 = idx & 15;
                int m = m0 + ph * 64 + rl;
                if (m < NN)
                    *(int4*)(obf + (size_t)m * ldo + n0 + c16 * 8) =
                        *(const int4*)(lds + rl * 128 + c16 * 8);
            }
            __syncthreads();
        }
    } else if (MODE == 1) {
        // fused GRU, 8-wave: wave's acc = r,z,i_n,hn for hcol = ct*32+wc*16+lm.
        // 2 phases over ct_off: write (a,z) 128x32 to LDS, blend with
        // coalesced h reads, store 32 hcols. Same rounding as r22.
        __syncthreads();   // acc final; sA4 reusable as scratch
        int hcol = ct * 32 + wc * 16 + lm;
        float rb = b0[hcol] + b1[hcol];
        float zb = b0[512 + hcol] + b1[512 + hcol];
        float ib = b0[1024 + hcol];
        float hb = b1[1024 + hcol];
#pragma unroll
        for (int g = 0; g < 2; ++g) {
            if (ct_off == g) {
                int c32 = wc * 16 + lm;
#pragma unroll
                for (int i = 0; i < 4; ++i)
#pragma unroll
                    for (int r = 0; r < 4; ++r) {
                        int rloc = wr * 64 + i * 16 + quad * 4 + r;
                        float rr = 1.f / (1.f + __expf(-(acc[i][0][r] + rb)));
                        float zz = 1.f / (1.f + __expf(-(acc[i][1][r] + zb)));
                        float nx = (acc[i][2][r] + ib) + rr * (acc[i][3][r] + hb);
                        float n = 1.f - 2.f / (__expf(2.f * nx) + 1.f);
                        ldsZ[rloc * 34 + c32] = make_float2((1.f - zz) * n, zz);
                    }
            }
            __syncthreads();
            int colb = bcol * 64 + g * 32;
#pragma unroll
            for (int q = 0; q < 2; ++q) {
                int idx = q * 512 + tid;          // 1024 4-col units
                int rl = idx >> 3, c4 = (idx & 7) * 4;
                int m = m0 + rl;
                if (m < NN) {
                    ulong1 hraw = *(const ulong1*)(A + (size_t)m * lda + 512 + colb + c4);
                    const __bf16* hb4 = (const __bf16*)&hraw;
                    const float2* pz = ldsZ + rl * 34 + c4;
                    __hip_bfloat16 ob[4];
#pragma unroll
                    for (int e = 0; e < 4; ++e) {
                        float2 az = pz[e];
                        ob[e] = __float2bfloat16(az.x + az.y * bfl(hb4[e]));
                    }
                    *(ulong1*)(obf + (size_t)m * ldo + colb + c4) = *(ulong1*)ob;
                }
            }
            __syncthreads();
        }
    } else {   // MODE 3: FC + column max
        if (tid < 128) sm[tid] = 0;
        __syncthreads();
#pragma unroll
        for (int j = 0; j < 4; ++j) {
            int c = wc * 64 + j * 16 + lm;
            float bias = b0[n0 + c];
            float mx = -INFINITY;
#pragma unroll
            for (int i = 0; i < 4; ++i) {
                int r0 = m0 + wr * 64 + i * 16 + quad * 4;
#pragma unroll
                for (int r = 0; r < 4; ++r) {
                    int m = r0 + r;
                    if (m < NN) mx = fmaxf(mx, acc[i][j][r] + bias);
                }
            }
            atomicMax(&sm[c], fenc(mx));
        }
        __syncthreads();
        if (tid < 128) atomicMax(&om[n0 + tid], sm[tid]);
    }
}

__global__ void writeout(const unsigned* __restrict__ om, float* __restrict__ o) {
    int c = threadIdx.x;
    o[c] = fdec(om[c]);
}

// ---------------- launch ----------------
extern "C" void kernel_launch(void* const* d_in, const int* in_sizes, int n_in,
                              void* d_out, int out_size, void* d_ws, size_t ws_size,
                              hipStream_t stream) {
    (void)in_sizes; (void)n_in; (void)out_size; (void)ws_size;
    const float* x    = (const float*)d_in[0];
    const int*   edges= (const int*)d_in[1];
    const float* Wmsg = (const float*)d_in[2];
    const float* bmsg = (const float*)d_in[3];
    const float* Wih  = (const float*)d_in[4];
    const float* Whh  = (const float*)d_in[5];
    const float* bih  = (const float*)d_in[6];
    const float* bhh  = (const float*)d_in[7];
    const float* fcW  = (const float*)d_in[8];
    const float* fcb  = (const float*)d_in[9];
    float* out = (float*)d_out;

    char* ws = (char*)d_ws;
    size_t off = 0;
    auto alloc = [&](size_t bytes) -> void* {
        void* p = ws + off; off += (bytes + 255) & ~(size_t)255; return p;
    };
    __hip_bfloat16* abA  = (__hip_bfloat16*)alloc((size_t)NN * 1024 * 2);   // 20.5 MB
    __hip_bfloat16* abB  = (__hip_bfloat16*)alloc((size_t)NN * 1024 * 2);   // 20.5 MB
    int*            bcnt = (int*)alloc((size_t)NN * NT * 4);                // 160 KB
    int*            bins = (int*)alloc((size_t)NN * NT * CAP * 4);          // 3.8 MB
    unsigned*       om   = (unsigned*)alloc(HD * 4);
    int4*           WmPK   = (int4*)alloc((size_t)2 * 131072 * 16);         // 4.2 MB
    int4*           WrznhPK= (int4*)alloc((size_t)2 * 262144 * 16);         // 8.4 MB
    int4*           WfPK   = (int4*)alloc((size_t)32768 * 16);              // 0.5 MB
    __hip_bfloat16* Msg  = (__hip_bfloat16*)alloc((size_t)NN * 2048 * 2);   // 41 MB
    // total ~99 MB

    hipMemsetAsync(bcnt, 0, (size_t)NN * NT * 4, stream);
    hipMemsetAsync(om, 0, HD * 4, stream);
    prep_all<<<1024 + 2048 + 128 + 5000 + 625, 256, 0, stream>>>(
        Wmsg, Wih, Whh, fcW, x, edges, WmPK, WrznhPK, WfPK, abA, bcnt, bins);

    for (int s = 0; s < 4; ++s) {
        int layer = s >> 1;
        __hip_bfloat16* cur = (s & 1) ? abB : abA;
        __hip_bfloat16* nxt = (s & 1) ? abA : abB;
        const int4* Wm = WmPK + (size_t)layer * 131072;
        const int4* Wz = WrznhPK + (size_t)layer * 262144;
        const float* bm = bmsg + (size_t)layer * 2048;
        const float* bi = bih + (size_t)layer * 1536;
        const float* bh = bhh + (size_t)layer * 1536;

        // Msg = h @ Wm^T  (out 2048, K=512)
        gemm<0><<<16 * GYROWS, 256, 0, stream>>>(cur + 512, 1024, 512, Wm,
            nullptr, nullptr, Msg, 2048, nullptr);
        // inc = gather(Msg) + cnt*bm -> cur[0:512]
        gather_msum<<<NN / 4, 256, 0, stream>>>(bins, bcnt, bm, Msg, cur);
        // fused GRU GEMM (8-wave, BN=256) -> nxt h-slot (bf16)
        gemm<1><<<8 * GYROWS, 512, 0, stream>>>(cur, 1024, 1024, Wz,
            bi, bh, nxt + 512, 1024, nullptr);
    }
    // FC + column max (final h in abA h-slot after 4 steps)
    gemm<3><<<4 * GYROWS, 256, 0, stream>>>(abA + 512, 1024, 512, WfPK,
        fcb, nullptr, nullptr, 0, om);
    writeout<<<1, 512, 0, stream>>>(om, out);
}